// Round 5
// baseline (428.833 us; speedup 1.0000x reference)
//
#include <hip/hip_runtime.h>
#include <math.h>
#include <limits.h>

#define NB1 8192    // sample histogram bins: float bits >> 19 (sign+exp+4 mantissa)
#define NB2 4096    // fine linear histogram bins over the band
#define VEC 4       // float4 per array per thread in main kernel (16 elements)

// loss = max(x,0) - x*t + log1p(exp(-|x|)) >= 0 ; p = sigmoid(x)
__device__ __forceinline__ void elem_f(float x, float t, float& l, float& p) {
    float e = __expf(-fabsf(x));
    l = fmaxf(x, 0.f) - x * t + __logf(1.f + e);
    float r = __builtin_amdgcn_rcpf(1.f + e);
    p = (x >= 0.f) ? r : e * r;
}

__device__ __forceinline__ unsigned agent_load_u32(const unsigned* p) {
    return __hip_atomic_load(p, __ATOMIC_RELAXED, __HIP_MEMORY_SCOPE_AGENT);
}
__device__ __forceinline__ float agent_load_f32(const float* p) {
    return __hip_atomic_load(p, __ATOMIC_RELAXED, __HIP_MEMORY_SCOPE_AGENT);
}

// ---------- k0: 1/16 chunked sample -> coarse bit-histogram; last block picks band ----------
__global__ __launch_bounds__(256) void sample_band_kernel(
    const float4* __restrict__ x4, const float4* __restrict__ t4,
    unsigned* __restrict__ H1, float* __restrict__ band,
    unsigned* __restrict__ done, int n4, long long ks, long long M)
{
    __shared__ unsigned lh[NB1];   // 32 KB
    for (int i = threadIdx.x; i < NB1; i += 256) lh[i] = 0u;
    __syncthreads();
    int tid = blockIdx.x * 256 + threadIdx.x;
    int stride = gridDim.x * 256;
    int S4 = n4 >> 4;              // sampled float4 pairs
    for (int i = tid; i < S4; i += stride) {
        int f4 = ((i >> 6) << 10) + (i & 63);   // contiguous 4KB chunks, 16x spaced
        if (f4 >= n4) continue;
        float4 xv = x4[f4];
        float4 tv = t4[f4];
        float xs[4] = {xv.x, xv.y, xv.z, xv.w};
        float ts[4] = {tv.x, tv.y, tv.z, tv.w};
        #pragma unroll
        for (int c = 0; c < 4; ++c) {
            float l, p;
            elem_f(xs[c], ts[c], l, p);
            atomicAdd(&lh[__float_as_uint(l) >> 19], 1u);
        }
    }
    __syncthreads();
    for (int i = threadIdx.x; i < NB1; i += 256) {
        unsigned c = lh[i];
        if (c) atomicAdd(&H1[i], c);
    }

    // --- last-block ticket ---
    __threadfence();
    __syncthreads();
    __shared__ unsigned ticket;
    if (threadIdx.x == 0)
        ticket = __hip_atomic_fetch_add(done, 1u, __ATOMIC_ACQ_REL, __HIP_MEMORY_SCOPE_AGENT);
    __syncthreads();
    if (ticket != gridDim.x - 1) return;
    __threadfence();

    // --- band selection (one block) ---
    for (int i = threadIdx.x; i < NB1; i += 256) lh[i] = agent_load_u32(&H1[i]);
    __syncthreads();
    if (threadIdx.x >= 64) return;

    int lane = threadIdx.x;
    int base = lane << 7;          // 128 bins per lane
    unsigned long long chunk = 0;
    for (int j = 0; j < 128; ++j) chunk += lh[base + j];
    unsigned long long s = chunk;  // inclusive suffix-scan across lanes
    #pragma unroll
    for (int off = 1; off < 64; off <<= 1) {
        unsigned long long v = __shfl_down(s, off);
        if (lane + off < 64) s += v;
    }
    unsigned long long above = s - chunk;

    int my_bhi = INT_MAX, my_blo = -1;
    unsigned long long c = above;
    for (int j = 127; j >= 0; --j) {
        unsigned h = lh[base + j];
        if ((long long)(c + h) < ks - M) my_bhi = base + j;
        if ((long long)c > ks + M && my_blo < 0) my_blo = base + j;
        c += h;
    }
    #pragma unroll
    for (int off = 32; off; off >>= 1) {
        int a = __shfl_down(my_bhi, off); my_bhi = min(my_bhi, a);
        int b = __shfl_down(my_blo, off); my_blo = max(my_blo, b);
    }
    if (lane == 0) {
        int bhi = (my_bhi == INT_MAX) ? (NB1 - 1) : my_bhi;
        int blo = my_blo;
        float vhi = __uint_as_float((unsigned)bhi << 19);
        float vlo = (blo < 0) ? 0.f : __uint_as_float((unsigned)(blo + 1) << 19);
        if (!(vlo < vhi)) vlo = 0.f;
        band[0] = vlo;   // kernel-boundary flush makes this visible to k1
        band[1] = vhi;
    }
}

__device__ __forceinline__ void process4(
    float4 xv, float4 tv, float vlo, float vhi, float scale,
    float& sp, float& spt, float& st, float& sgt, unsigned& cnt,
    unsigned* __restrict__ hist2)
{
    float xs[4] = {xv.x, xv.y, xv.z, xv.w};
    float ts[4] = {tv.x, tv.y, tv.z, tv.w};
    #pragma unroll
    for (int c = 0; c < 4; ++c) {
        float l, p;
        elem_f(xs[c], ts[c], l, p);
        sp += p; spt += p * ts[c]; st += ts[c];
        if (l >= vhi) { cnt++; sgt += l; }
        else if (l >= vlo) {
            int b = min((int)((l - vlo) * scale), NB2 - 1);
            atomicAdd(&hist2[b], 1u);
        }
    }
}

// ---------- k1: full pass; per-block private slots; last block resolves + emits ----------
__global__ __launch_bounds__(256, 8) void main_final_kernel(
    const float4* __restrict__ x4, const float4* __restrict__ t4,
    const float* __restrict__ band, unsigned* __restrict__ hist2,
    float* __restrict__ q0, float* __restrict__ q1,
    float* __restrict__ q2, float* __restrict__ q3, unsigned* __restrict__ qc,
    unsigned* __restrict__ done,
    const float* __restrict__ xg, const float* __restrict__ tg,
    int n, int n4, float* __restrict__ out, long long k)
{
    float vlo = band[0], vhi = band[1];
    float scale = (float)NB2 / (vhi - vlo);

    int base = blockIdx.x * (256 * VEC) + threadIdx.x;
    float sp = 0.f, spt = 0.f, st = 0.f, sgt = 0.f;
    unsigned cnt = 0;

    bool full = (blockIdx.x + 1) * (256 * VEC) <= n4;   // block-uniform
    if (full) {
        float4 xv[VEC], tv[VEC];
        #pragma unroll
        for (int j = 0; j < VEC; ++j) xv[j] = x4[base + j * 256];
        #pragma unroll
        for (int j = 0; j < VEC; ++j) tv[j] = t4[base + j * 256];
        #pragma unroll
        for (int j = 0; j < VEC; ++j)
            process4(xv[j], tv[j], vlo, vhi, scale, sp, spt, st, sgt, cnt, hist2);
    } else {
        for (int j = 0; j < VEC; ++j) {
            int idx = base + j * 256;
            if (idx < n4)
                process4(x4[idx], t4[idx], vlo, vhi, scale, sp, spt, st, sgt, cnt, hist2);
        }
    }
    // scalar tail (n % 4) on block 0
    int tail0 = n4 << 2;
    if (blockIdx.x == 0 && threadIdx.x < (n - tail0)) {
        float x = xg[tail0 + threadIdx.x], t = tg[tail0 + threadIdx.x];
        float l, p;
        elem_f(x, t, l, p);
        sp += p; spt += p * t; st += t;
        if (l >= vhi) { cnt++; sgt += l; }
        else if (l >= vlo) {
            int b = min((int)((l - vlo) * scale), NB2 - 1);
            atomicAdd(&hist2[b], 1u);
        }
    }

    // wave -> block reduce -> ONE private slot write per block
    #pragma unroll
    for (int off = 32; off; off >>= 1) {
        sp  += __shfl_down(sp,  off);
        spt += __shfl_down(spt, off);
        st  += __shfl_down(st,  off);
        sgt += __shfl_down(sgt, off);
        cnt += __shfl_down(cnt, off);
    }
    __shared__ float    rs[4][4];
    __shared__ unsigned rc[4];
    int w = threadIdx.x >> 6;
    if ((threadIdx.x & 63) == 0) {
        rs[w][0] = sp; rs[w][1] = spt; rs[w][2] = st; rs[w][3] = sgt; rc[w] = cnt;
    }
    __syncthreads();
    if (threadIdx.x == 0) {
        float a0 = 0, a1 = 0, a2 = 0, a3 = 0;
        unsigned c = 0;
        #pragma unroll
        for (int i = 0; i < 4; ++i) {
            a0 += rs[i][0]; a1 += rs[i][1]; a2 += rs[i][2]; a3 += rs[i][3]; c += rc[i];
        }
        q0[blockIdx.x] = a0; q1[blockIdx.x] = a1; q2[blockIdx.x] = a2;
        q3[blockIdx.x] = a3; qc[blockIdx.x] = c;
    }

    // --- last-block ticket ---
    __threadfence();
    __syncthreads();
    __shared__ unsigned ticket;
    if (threadIdx.x == 0)
        ticket = __hip_atomic_fetch_add(done, 1u, __ATOMIC_ACQ_REL, __HIP_MEMORY_SCOPE_AGENT);
    __syncthreads();
    if (ticket != gridDim.x - 1) return;
    __threadfence();

    // --- final resolve (one block, 256 threads) ---
    __shared__ unsigned lh2[NB2];       // 16 KB
    __shared__ double red[4][5];
    __shared__ double fin[5];
    for (int i = threadIdx.x; i < NB2; i += 256) lh2[i] = agent_load_u32(&hist2[i]);

    int nblocks = gridDim.x;
    double a0 = 0, a1 = 0, a2 = 0, a3 = 0, a4 = 0;
    for (int i = threadIdx.x; i < nblocks; i += 256) {
        a0 += (double)agent_load_f32(&q0[i]);
        a1 += (double)agent_load_f32(&q1[i]);
        a2 += (double)agent_load_f32(&q2[i]);
        a3 += (double)agent_load_f32(&q3[i]);
        a4 += (double)agent_load_u32(&qc[i]);
    }
    #pragma unroll
    for (int off = 32; off; off >>= 1) {
        a0 += __shfl_down(a0, off); a1 += __shfl_down(a1, off);
        a2 += __shfl_down(a2, off); a3 += __shfl_down(a3, off);
        a4 += __shfl_down(a4, off);
    }
    if ((threadIdx.x & 63) == 0) {
        red[w][0] = a0; red[w][1] = a1; red[w][2] = a2; red[w][3] = a3; red[w][4] = a4;
    }
    __syncthreads();
    if (threadIdx.x == 0) {
        double f0 = 0, f1 = 0, f2 = 0, f3 = 0, f4 = 0;
        #pragma unroll
        for (int i = 0; i < 4; ++i) {
            f0 += red[i][0]; f1 += red[i][1]; f2 += red[i][2];
            f3 += red[i][3]; f4 += red[i][4];
        }
        fin[0] = f0; fin[1] = f1; fin[2] = f2; fin[3] = f3; fin[4] = f4;
    }
    __syncthreads();
    if (threadIdx.x >= 64) return;

    int lane = threadIdx.x;
    double SP = fin[0], SPT = fin[1], ST = fin[2], SGT = fin[3];
    long long CNT = (long long)fin[4];

    double dvlo = (double)vlo, dvhi = (double)vhi;
    double binw = (dvhi - dvlo) / NB2;
    long long k2 = k - CNT;

    int base2 = lane << 6;              // 64 bins per lane (LDS-resident)
    unsigned long long cchunk = 0;
    double wchunk = 0.0;
    for (int j = 0; j < 64; ++j) {
        unsigned h = lh2[base2 + j];
        cchunk += h;
        wchunk += (double)h * (dvlo + (base2 + j + 0.5) * binw);
    }
    unsigned long long cs = cchunk;
    double wsum = wchunk;
    #pragma unroll
    for (int off = 1; off < 64; off <<= 1) {
        unsigned long long cv = __shfl_down(cs, off);
        double wv = __shfl_down(wsum, off);
        if (lane + off < 64) { cs += cv; wsum += wv; }
    }
    unsigned long long total = __shfl(cs, 0);
    double wtotal = __shfl(wsum, 0);

    double I = SPT, U = SP + ST;
    double dice_part = 0.5 * (1.0 - (2.0 * I + 1e-6) / (U + 1e-6));

    if (k2 <= 0) {
        if (lane == 0) out[0] = (float)(SGT / (double)k + dice_part);
        return;
    }
    if ((unsigned long long)k2 > total) {
        if (lane == 0) {
            double sum_top = SGT + wtotal + (double)(k2 - (long long)total) * dvlo;
            out[0] = (float)(sum_top / (double)k + dice_part);
        }
        return;
    }
    unsigned long long c = cs - cchunk;
    double wacc = wsum - wchunk;
    for (int j = 63; j >= 0; --j) {
        unsigned h = lh2[base2 + j];
        double val = dvlo + (base2 + j + 0.5) * binw;
        if (c < (unsigned long long)k2 && (unsigned long long)k2 <= c + h) {
            double sum_top = SGT + wacc + (double)((long long)k2 - (long long)c) * val;
            out[0] = (float)(sum_top / (double)k + dice_part);
        }
        c += h;
        wacc += (double)h * val;
    }
}

extern "C" void kernel_launch(void* const* d_in, const int* in_sizes, int n_in,
                              void* d_out, int out_size, void* d_ws, size_t ws_size,
                              hipStream_t stream)
{
    const float* x = (const float*)d_in[0];
    const float* t = (const float*)d_in[1];
    float* out = (float*)d_out;
    int n = in_sizes[0];
    int n4 = n >> 2;
    long long k = (long long)((double)n * 0.2);   // Python int() truncation
    if (k < 1) k = 1;

    long long S = (long long)(n4 >> 4) * 4;       // sampled element count
    long long ks = (S > 0) ? (long long)((double)k * (double)S / (double)n) : 0;
    long long M = 4096;                           // ~13 sigma sample-rank margin

    int tilesz = 256 * VEC;                       // float4 per tile
    int grid = (n4 + tilesz - 1) / tilesz;
    if (grid < 1) grid = 1;

    unsigned char* ws = (unsigned char*)d_ws;
    unsigned* H1    = (unsigned*)(ws);                 // 32 KB
    unsigned* hist2 = (unsigned*)(ws + 32768);         // 16 KB
    float*    band  = (float*)(ws + 49152);            // 8 B
    unsigned* done0 = (unsigned*)(ws + 49160);
    unsigned* done1 = (unsigned*)(ws + 49164);
    size_t po = 49408;                                 // partials base (256-aligned)
    size_t pstride = (((size_t)grid * 4) + 255) & ~(size_t)255;
    float*    q0 = (float*)(ws + po);
    float*    q1 = (float*)(ws + po + pstride);
    float*    q2 = (float*)(ws + po + 2 * pstride);
    float*    q3 = (float*)(ws + po + 3 * pstride);
    unsigned* qc = (unsigned*)(ws + po + 4 * pstride);

    hipMemsetAsync(d_ws, 0, 49408, stream);          // H1 + hist2 + band + tickets

    sample_band_kernel<<<256, 256, 0, stream>>>((const float4*)x, (const float4*)t,
                                                H1, band, done0, n4, ks, M);
    main_final_kernel<<<grid, 256, 0, stream>>>((const float4*)x, (const float4*)t,
                                                band, hist2, q0, q1, q2, q3, qc, done1,
                                                x, t, n, n4, out, k);
}

// Round 6
// 138.372 us; speedup vs baseline: 3.0991x; 3.0991x over previous
//
#include <hip/hip_runtime.h>
#include <math.h>
#include <limits.h>

#define NB1 8192    // sample histogram bins: float bits >> 19 (sign+exp+4 mantissa)
#define NB2 4096    // fine linear histogram bins over the band
#define VEC 4       // float4 per array per thread in main kernel (16 elements)

// loss = max(x,0) - x*t + log1p(exp(-|x|)) >= 0 ; p = sigmoid(x)
__device__ __forceinline__ void elem_f(float x, float t, float& l, float& p) {
    float e = __expf(-fabsf(x));
    l = fmaxf(x, 0.f) - x * t + __logf(1.f + e);
    float r = __builtin_amdgcn_rcpf(1.f + e);
    p = (x >= 0.f) ? r : e * r;
}

// ---------- k0: 1/16 chunked sample -> coarse bit-histogram ----------
// sample i -> float4 index (i>>6)*1024 + (i&63): contiguous 4KB chunks, 16x apart.
// Each thread handles exactly 2 sampled pairs, loads pre-issued (4x16B in flight).
__global__ __launch_bounds__(256) void sample_kernel(
    const float4* __restrict__ x4, const float4* __restrict__ t4,
    unsigned* __restrict__ H1, int n4)
{
    __shared__ unsigned lh[NB1];   // 32 KB
    for (int i = threadIdx.x; i < NB1; i += 256) lh[i] = 0u;
    __syncthreads();

    int nth = gridDim.x * 256;
    int tid = blockIdx.x * 256 + threadIdx.x;
    int S4 = n4 >> 4;              // sampled float4 pairs
    int i0 = tid, i1 = tid + nth;

    float4 xa, ta, xb, tb;
    bool v0 = i0 < S4, v1 = i1 < S4;
    if (v0) {
        int f4 = ((i0 >> 6) << 10) + (i0 & 63);
        xa = x4[f4]; ta = t4[f4];
    }
    if (v1) {
        int f4 = ((i1 >> 6) << 10) + (i1 & 63);
        xb = x4[f4]; tb = t4[f4];
    }
    if (v0) {
        float xs[4] = {xa.x, xa.y, xa.z, xa.w};
        float ts[4] = {ta.x, ta.y, ta.z, ta.w};
        #pragma unroll
        for (int c = 0; c < 4; ++c) {
            float l, p; elem_f(xs[c], ts[c], l, p);
            atomicAdd(&lh[__float_as_uint(l) >> 19], 1u);
        }
    }
    if (v1) {
        float xs[4] = {xb.x, xb.y, xb.z, xb.w};
        float ts[4] = {tb.x, tb.y, tb.z, tb.w};
        #pragma unroll
        for (int c = 0; c < 4; ++c) {
            float l, p; elem_f(xs[c], ts[c], l, p);
            atomicAdd(&lh[__float_as_uint(l) >> 19], 1u);
        }
    }
    __syncthreads();
    for (int i = threadIdx.x; i < NB1; i += 256) {
        unsigned c = lh[i];
        if (c) atomicAdd(&H1[i], c);
    }
}

// ---------- k1: pick value band [vlo, vhi) containing the kth value ----------
__global__ __launch_bounds__(256) void band_kernel(
    const unsigned* __restrict__ H1, float* __restrict__ band,
    long long ks, long long M)
{
    __shared__ unsigned lh[NB1];   // 32 KB
    const uint4* hv = (const uint4*)H1;
    uint4* lv = (uint4*)lh;
    for (int i = threadIdx.x; i < NB1 / 4; i += 256) lv[i] = hv[i];
    __syncthreads();
    if (threadIdx.x >= 64) return;

    int lane = threadIdx.x;
    int base = lane << 7;          // 128 bins per lane
    unsigned long long chunk = 0;
    for (int j = 0; j < 128; ++j) chunk += lh[base + j];
    unsigned long long s = chunk;  // inclusive suffix-scan across lanes
    #pragma unroll
    for (int off = 1; off < 64; off <<= 1) {
        unsigned long long v = __shfl_down(s, off);
        if (lane + off < 64) s += v;
    }
    unsigned long long above = s - chunk;

    int my_bhi = INT_MAX, my_blo = -1;
    unsigned long long c = above;
    for (int j = 127; j >= 0; --j) {
        unsigned h = lh[base + j];
        if ((long long)(c + h) < ks - M) my_bhi = base + j;
        if ((long long)c > ks + M && my_blo < 0) my_blo = base + j;
        c += h;
    }
    #pragma unroll
    for (int off = 32; off; off >>= 1) {
        int a = __shfl_down(my_bhi, off); my_bhi = min(my_bhi, a);
        int b = __shfl_down(my_blo, off); my_blo = max(my_blo, b);
    }
    if (lane == 0) {
        int bhi = (my_bhi == INT_MAX) ? (NB1 - 1) : my_bhi;
        int blo = my_blo;
        float vhi = __uint_as_float((unsigned)bhi << 19);
        float vlo = (blo < 0) ? 0.f : __uint_as_float((unsigned)(blo + 1) << 19);
        if (!(vlo < vhi)) vlo = 0.f;
        band[0] = vlo;
        band[1] = vhi;
    }
}

__device__ __forceinline__ void process4(
    float4 xv, float4 tv, float vlo, float vhi, float scale,
    float& sp, float& spt, float& st, float& sgt, unsigned& cnt,
    unsigned* __restrict__ hist2)
{
    float xs[4] = {xv.x, xv.y, xv.z, xv.w};
    float ts[4] = {tv.x, tv.y, tv.z, tv.w};
    #pragma unroll
    for (int c = 0; c < 4; ++c) {
        float l, p;
        elem_f(xs[c], ts[c], l, p);
        sp += p; spt += p * ts[c]; st += ts[c];
        if (l >= vhi) { cnt++; sgt += l; }
        else if (l >= vlo) {
            int b = min((int)((l - vlo) * scale), NB2 - 1);
            atomicAdd(&hist2[b], 1u);
        }
    }
}

// ---------- k2: single full pass; per-block partials to private slots ----------
// (256,4): 128-VGPR budget so all 2*VEC dwordx4 loads issue before first use.
__global__ __launch_bounds__(256, 4) void main_kernel(
    const float4* __restrict__ x4, const float4* __restrict__ t4,
    const float* __restrict__ band, unsigned* __restrict__ hist2,
    float* __restrict__ q0, float* __restrict__ q1,
    float* __restrict__ q2, float* __restrict__ q3, unsigned* __restrict__ qc,
    const float* __restrict__ xg, const float* __restrict__ tg,
    int n, int n4)
{
    float vlo = band[0], vhi = band[1];
    float scale = (float)NB2 / (vhi - vlo);

    int base = blockIdx.x * (256 * VEC) + threadIdx.x;
    float sp = 0.f, spt = 0.f, st = 0.f, sgt = 0.f;
    unsigned cnt = 0;

    bool full = (blockIdx.x + 1) * (256 * VEC) <= n4;   // block-uniform
    if (full) {
        float4 xv[VEC], tv[VEC];
        #pragma unroll
        for (int j = 0; j < VEC; ++j) xv[j] = x4[base + j * 256];
        #pragma unroll
        for (int j = 0; j < VEC; ++j) tv[j] = t4[base + j * 256];
        #pragma unroll
        for (int j = 0; j < VEC; ++j)
            process4(xv[j], tv[j], vlo, vhi, scale, sp, spt, st, sgt, cnt, hist2);
    } else {
        for (int j = 0; j < VEC; ++j) {
            int idx = base + j * 256;
            if (idx < n4)
                process4(x4[idx], t4[idx], vlo, vhi, scale, sp, spt, st, sgt, cnt, hist2);
        }
    }
    // scalar tail (n % 4) on block 0
    int tail0 = n4 << 2;
    if (blockIdx.x == 0 && threadIdx.x < (n - tail0)) {
        float x = xg[tail0 + threadIdx.x], t = tg[tail0 + threadIdx.x];
        float l, p;
        elem_f(x, t, l, p);
        sp += p; spt += p * t; st += t;
        if (l >= vhi) { cnt++; sgt += l; }
        else if (l >= vlo) {
            int b = min((int)((l - vlo) * scale), NB2 - 1);
            atomicAdd(&hist2[b], 1u);
        }
    }

    // wave -> block reduce, then ONE private slot write per block
    #pragma unroll
    for (int off = 32; off; off >>= 1) {
        sp  += __shfl_down(sp,  off);
        spt += __shfl_down(spt, off);
        st  += __shfl_down(st,  off);
        sgt += __shfl_down(sgt, off);
        cnt += __shfl_down(cnt, off);
    }
    __shared__ float    rs[4][4];
    __shared__ unsigned rc[4];
    int w = threadIdx.x >> 6;
    if ((threadIdx.x & 63) == 0) {
        rs[w][0] = sp; rs[w][1] = spt; rs[w][2] = st; rs[w][3] = sgt; rc[w] = cnt;
    }
    __syncthreads();
    if (threadIdx.x == 0) {
        float a0 = 0, a1 = 0, a2 = 0, a3 = 0;
        unsigned c = 0;
        #pragma unroll
        for (int i = 0; i < 4; ++i) {
            a0 += rs[i][0]; a1 += rs[i][1]; a2 += rs[i][2]; a3 += rs[i][3]; c += rc[i];
        }
        q0[blockIdx.x] = a0; q1[blockIdx.x] = a1; q2[blockIdx.x] = a2;
        q3[blockIdx.x] = a3; qc[blockIdx.x] = c;
    }
}

// ---------- k3: reduce partials + resolve threshold bin + emit ----------
__global__ __launch_bounds__(1024) void final_kernel(
    const unsigned* __restrict__ hist2, const float* __restrict__ band,
    const float* __restrict__ q0, const float* __restrict__ q1,
    const float* __restrict__ q2, const float* __restrict__ q3,
    const unsigned* __restrict__ qc, int nblocks,
    float* __restrict__ out, long long k)
{
    __shared__ unsigned lh[NB2];        // 16 KB
    __shared__ double red[16][5];
    __shared__ double fin[5];

    for (int i = threadIdx.x; i < NB2; i += 1024) lh[i] = hist2[i];

    double a0 = 0, a1 = 0, a2 = 0, a3 = 0, a4 = 0;
    for (int i = threadIdx.x; i < nblocks; i += 1024) {
        a0 += (double)q0[i]; a1 += (double)q1[i]; a2 += (double)q2[i];
        a3 += (double)q3[i]; a4 += (double)qc[i];
    }
    #pragma unroll
    for (int off = 32; off; off >>= 1) {
        a0 += __shfl_down(a0, off); a1 += __shfl_down(a1, off);
        a2 += __shfl_down(a2, off); a3 += __shfl_down(a3, off);
        a4 += __shfl_down(a4, off);
    }
    int w = threadIdx.x >> 6;
    if ((threadIdx.x & 63) == 0) {
        red[w][0] = a0; red[w][1] = a1; red[w][2] = a2; red[w][3] = a3; red[w][4] = a4;
    }
    __syncthreads();
    if (threadIdx.x == 0) {
        double f0 = 0, f1 = 0, f2 = 0, f3 = 0, f4 = 0;
        for (int i = 0; i < 16; ++i) {
            f0 += red[i][0]; f1 += red[i][1]; f2 += red[i][2];
            f3 += red[i][3]; f4 += red[i][4];
        }
        fin[0] = f0; fin[1] = f1; fin[2] = f2; fin[3] = f3; fin[4] = f4;
    }
    __syncthreads();
    if (threadIdx.x >= 64) return;

    int lane = threadIdx.x;
    double SP = fin[0], SPT = fin[1], ST = fin[2], SGT = fin[3];
    long long CNT = (long long)fin[4];

    double vlo = (double)band[0], vhi = (double)band[1];
    double binw = (vhi - vlo) / NB2;
    long long k2 = k - CNT;

    int base = lane << 6;               // 64 bins per lane (LDS-resident)
    unsigned long long cchunk = 0;
    double wchunk = 0.0;
    for (int j = 0; j < 64; ++j) {
        unsigned h = lh[base + j];
        cchunk += h;
        wchunk += (double)h * (vlo + (base + j + 0.5) * binw);
    }
    unsigned long long cs = cchunk;
    double wsum = wchunk;
    #pragma unroll
    for (int off = 1; off < 64; off <<= 1) {
        unsigned long long cv = __shfl_down(cs, off);
        double wv = __shfl_down(wsum, off);
        if (lane + off < 64) { cs += cv; wsum += wv; }
    }
    unsigned long long total = __shfl(cs, 0);
    double wtotal = __shfl(wsum, 0);

    double I = SPT, U = SP + ST;
    double dice_part = 0.5 * (1.0 - (2.0 * I + 1e-6) / (U + 1e-6));

    if (k2 <= 0) {
        if (lane == 0) out[0] = (float)(SGT / (double)k + dice_part);
        return;
    }
    if ((unsigned long long)k2 > total) {
        if (lane == 0) {
            double sum_top = SGT + wtotal + (double)(k2 - (long long)total) * vlo;
            out[0] = (float)(sum_top / (double)k + dice_part);
        }
        return;
    }
    unsigned long long c = cs - cchunk;
    double wacc = wsum - wchunk;
    for (int j = 63; j >= 0; --j) {
        unsigned h = lh[base + j];
        double val = vlo + (base + j + 0.5) * binw;
        if (c < (unsigned long long)k2 && (unsigned long long)k2 <= c + h) {
            double sum_top = SGT + wacc + (double)((long long)k2 - (long long)c) * val;
            out[0] = (float)(sum_top / (double)k + dice_part);
        }
        c += h;
        wacc += (double)h * val;
    }
}

extern "C" void kernel_launch(void* const* d_in, const int* in_sizes, int n_in,
                              void* d_out, int out_size, void* d_ws, size_t ws_size,
                              hipStream_t stream)
{
    const float* x = (const float*)d_in[0];
    const float* t = (const float*)d_in[1];
    float* out = (float*)d_out;
    int n = in_sizes[0];
    int n4 = n >> 2;
    long long k = (long long)((double)n * 0.2);   // Python int() truncation
    if (k < 1) k = 1;

    long long S = (long long)(n4 >> 4) * 4;       // sampled element count
    long long ks = (S > 0) ? (long long)((double)k * (double)S / (double)n) : 0;
    long long M = 4096;                           // ~13 sigma sample-rank margin

    int tilesz = 256 * VEC;                       // float4 per tile
    int grid = (n4 + tilesz - 1) / tilesz;
    if (grid < 1) grid = 1;

    int S4 = n4 >> 4;                             // sampled float4 pairs
    int sgrid = (S4 + 511) / 512;                 // 2 pairs per thread
    if (sgrid < 1) sgrid = 1;

    unsigned char* ws = (unsigned char*)d_ws;
    unsigned* H1    = (unsigned*)(ws);                 // 32 KB
    unsigned* hist2 = (unsigned*)(ws + 32768);         // 16 KB
    float*    band  = (float*)(ws + 49152);            // 8 B
    size_t po = 50176;                                 // partials base (256-aligned)
    size_t pstride = (((size_t)grid * 4) + 255) & ~(size_t)255;
    float*    q0 = (float*)(ws + po);
    float*    q1 = (float*)(ws + po + pstride);
    float*    q2 = (float*)(ws + po + 2 * pstride);
    float*    q3 = (float*)(ws + po + 3 * pstride);
    unsigned* qc = (unsigned*)(ws + po + 4 * pstride);

    hipMemsetAsync(d_ws, 0, 49152, stream);          // H1 + hist2 only

    sample_kernel<<<sgrid, 256, 0, stream>>>((const float4*)x, (const float4*)t, H1, n4);
    band_kernel<<<1, 256, 0, stream>>>(H1, band, ks, M);
    main_kernel<<<grid, 256, 0, stream>>>((const float4*)x, (const float4*)t,
                                          band, hist2, q0, q1, q2, q3, qc, x, t, n, n4);
    final_kernel<<<1, 1024, 0, stream>>>(hist2, band, q0, q1, q2, q3, qc, grid, out, k);
}